// Round 6
// baseline (324.334 us; speedup 1.0000x reference)
//
#include <hip/hip_runtime.h>
#include <hip/hip_bf16.h>
#include <math.h>

#define B_   2
#define S_   2048
#define HID_ 2048
#define NH_  32
#define NKV_ 8
#define D_   64
#define G_   (NH_/NKV_)
#define M_   (B_*S_)      // 4096

typedef __hip_bfloat16 bf16;
typedef short bf16x8 __attribute__((ext_vector_type(8)));
typedef float f32x4  __attribute__((ext_vector_type(4)));
typedef unsigned short u16x4 __attribute__((ext_vector_type(4)));

__device__ inline unsigned short f2bfu(float f){
    __hip_bfloat16 h = __float2bfloat16(f);
    return __builtin_bit_cast(unsigned short, h);
}

__device__ __forceinline__ float fexp2(float x){
#if __has_builtin(__builtin_amdgcn_exp2f)
    return __builtin_amdgcn_exp2f(x);
#else
    return exp2f(x);
#endif
}

// async global->LDS, 16B per lane. LDS dest = wave-uniform base + lane*16.
__device__ __forceinline__ void async16(const void* g, void* l) {
    __builtin_amdgcn_global_load_lds(
        (const __attribute__((address_space(1))) unsigned int*)g,
        (__attribute__((address_space(3))) unsigned int*)l, 16, 0, 0);
}

// XOR swizzle for 128B (64 ushort) rows (attn): spreads 16B slots across banks.
#define SWZ(r, c) ((c) ^ (((r) & 7) << 3))

// raw barrier + counted waitcnt
#define S_BARRIER() asm volatile("s_barrier" ::: "memory")
__device__ __forceinline__ void vmwait4(){ asm volatile("s_waitcnt vmcnt(4)" ::: "memory"); }
__device__ __forceinline__ void vmwait0(){ asm volatile("s_waitcnt vmcnt(0)" ::: "memory"); }

// ---------------------------------------------------------------------------
// Transpose + convert body: dst[n][k] (bf16) = src_seg[k][n] (fp32).
// ---------------------------------------------------------------------------
__device__ __forceinline__ void wtrans_body(
    const float* __restrict__ s0, int N0,
    const float* __restrict__ s1, int N1,
    const float* __restrict__ s2, int N2,
    bf16* __restrict__ dst, int K, int bx, int by,
    unsigned short* __restrict__ tbuf)
{
    unsigned short (*t)[65] = (unsigned short (*)[65])tbuf;
    const int ntile = bx * 64, ktile = by * 64;
    const float* src; int nloc, Nseg;
    if (ntile < N0)           { src = s0; nloc = ntile;           Nseg = N0; }
    else if (ntile < N0 + N1) { src = s1; nloc = ntile - N0;      Nseg = N1; }
    else                      { src = s2; nloc = ntile - N0 - N1; Nseg = N2; }
    const int r  = threadIdx.x >> 4;
    const int c4 = (threadIdx.x & 15) * 4;
    #pragma unroll
    for (int p = 0; p < 4; p++) {
        const int k = p * 16 + r;
        const float4 f = *(const float4*)(src + (size_t)(ktile + k) * Nseg + nloc + c4);
        t[k][c4+0] = f2bfu(f.x); t[k][c4+1] = f2bfu(f.y);
        t[k][c4+2] = f2bfu(f.z); t[k][c4+3] = f2bfu(f.w);
    }
    __syncthreads();
    #pragma unroll
    for (int p = 0; p < 4; p++) {
        const int n = p * 16 + r;
        u16x4 u = { t[c4+0][n], t[c4+1][n], t[c4+2][n], t[c4+3][n] };
        *(u16x4*)((unsigned short*)dst + (size_t)(ntile + n) * K + ktile + c4) = u;
    }
}

// ---------------------------------------------------------------------------
// Fused prep: blocks [0,4096) fp32->bf16 convert of hidden_states;
//             [4096,5632) wtrans of wq|wk|wv -> wqkvT;
//             [5632,5888) RoPE cos/sin tables.
// ---------------------------------------------------------------------------
__global__ __launch_bounds__(256) void prep_k(
    const float* __restrict__ hs, bf16* __restrict__ hs_b,
    const float* __restrict__ wq, const float* __restrict__ wk,
    const float* __restrict__ wv, bf16* __restrict__ wqkvT,
    const int* __restrict__ pos, float* __restrict__ ctab,
    float* __restrict__ stab)
{
    __shared__ unsigned short tbuf[64 * 65];
    const int bid = blockIdx.x;
    if (bid < 4096) {
        const int i = (bid * 256 + threadIdx.x) * 8;
        const float4 a = *(const float4*)(hs + i);
        const float4 b = *(const float4*)(hs + i + 4);
        uint4 u;
        u.x = (unsigned)f2bfu(a.x) | ((unsigned)f2bfu(a.y) << 16);
        u.y = (unsigned)f2bfu(a.z) | ((unsigned)f2bfu(a.w) << 16);
        u.z = (unsigned)f2bfu(b.x) | ((unsigned)f2bfu(b.y) << 16);
        u.w = (unsigned)f2bfu(b.z) | ((unsigned)f2bfu(b.w) << 16);
        *(uint4*)((unsigned short*)hs_b + i) = u;
    } else if (bid < 5632) {
        const int t = bid - 4096;                       // 0..1535 (48 x 32)
        wtrans_body(wq, 2048, wk, 512, wv, 512, wqkvT, HID_,
                    t % 48, t / 48, tbuf);
    } else {
        const int idx = (bid - 5632) * 256 + threadIdx.x;
        const int s = idx >> 5, i = idx & 31;
        const int is64 = (pos[1] == 0);
        const int p = is64 ? pos[2 * s] : pos[s];
        const double inv = exp(-(double)i * (log(150000.0) / 32.0));
        const double f = (double)p * inv;
        ctab[idx] = (float)cos(f);
        stab[idx] = (float)sin(f);
    }
}

// ---------------------------------------------------------------------------
// 4-phase pipelined MFMA GEMM: C = A[M,2048] @ WT[N,2048]^T.
// BM x 256 tile, BK=64, 8 waves (2M x 4N), double-buffered LDS.
// 2 phases per K-tile, 32 (BM=256) / 16 (BM=128) MFMA per barrier pair
// (toward AITER's ~32 MFMA/barrier). Counted vmcnt(4) twice per 2-tile
// iteration, never 0 mid-loop. Stage ledger (insts in flight), BM=256:
//   prologue A0:4+B0:4+B1:4=12, wait4 -> leaves B1:4.
//   ph0 +A(tb):4=8; ph1 +B(ta+2):4=12, wait4 drains B1+A(tb) (buf1 ready),
//   leaves B(ta+2):4; ph2 +A(ta+2):4=8; ph3 +B(tb+2):4=12, wait4 drains
//   B(ta+2)+A(ta+2) (buf0 ready) -> invariant. BM=128 same with A:2.
// Write-after-read: every stage targets a region whose last ds_read was
// before an intervening barrier (B consumed to regs in ph0/ph2).
// T1 XCD-chunked remap; XOR chunk swizzle both-sides.
// MODE 0: QKV epilogue (Q: RoPE + 0.125*log2e; K: RoPE; V: transposed store).
// MODE 1: OUT epilogue (fp32 + bias b0), BM=128.
// ---------------------------------------------------------------------------
__device__ __forceinline__ void slab64(
    const bf16* __restrict__ g, int grow0, int k0,
    unsigned short* lds, int wave, int lane)
{
    const int rr = wave * 8 + (lane >> 3);
    const int cc = ((lane & 7) ^ (lane >> 3)) * 8;
    async16(g + (size_t)(grow0 + rr) * 2048 + k0 + cc, lds + wave * 512);
}

template<int MODE, int BM>
__global__ __launch_bounds__(512, 2) void gemm4p_k(
    const bf16* __restrict__ A, const bf16* __restrict__ WT,
    const float* __restrict__ b0, const float* __restrict__ b1,
    const float* __restrict__ b2,
    bf16* __restrict__ Cq, bf16* __restrict__ Ck, bf16* __restrict__ Cv,
    float* __restrict__ Cout,
    const float* __restrict__ ctab, const float* __restrict__ stab)
{
    constexpr int MT = BM / 32;    // m-frags per wave
    constexpr int PM = MT / 2;     // m-frags per phase (half-tile)
    constexpr int LA = BM * 64;    // ushorts per A buffer
    constexpr int LB = 256 * 64;   // ushorts per B buffer
    constexpr int NT = 32;         // K-tiles (2048/64)
    __shared__ unsigned short sA[2 * LA];
    __shared__ unsigned short sB[2 * LB];

    const int tid  = threadIdx.x;
    const int wave = tid >> 6, lane = tid & 63;
    const int li   = lane & 15, lj = lane >> 4;
    const int wm   = wave >> 2, wn = wave & 3;

    // T1: XCD-chunked bijective remap (nwg % 8 == 0 for both instantiations).
    const int nbx = gridDim.x, nby = gridDim.y;
    const int lin = blockIdx.y * nbx + blockIdx.x;
    const int qq  = (nbx * nby) >> 3;
    const int logical = (lin & 7) * qq + (lin >> 3);
    const int m0 = (logical % nby) * BM;
    const int n0 = (logical / nby) * 256;
    const int swz = li & 7;

    f32x4 acc[MT][4];
    #pragma unroll
    for (int i = 0; i < MT; ++i)
        #pragma unroll
        for (int j = 0; j < 4; ++j)
            acc[i][j] = (f32x4){0.f, 0.f, 0.f, 0.f};

    bf16x8 bfr[4][2];

    auto stageAf = [&](int t) {
        unsigned short* l = sA + (t & 1) * LA;
        const int k0 = (t & (NT - 1)) * 64;
        #pragma unroll
        for (int i = 0; i < BM / 64; ++i)
            slab64(A, m0 + i * 64, k0, l + i * 64 * 64, wave, lane);
    };
    auto stageBf = [&](int t) {
        unsigned short* l = sB + (t & 1) * LB;
        const int k0 = (t & (NT - 1)) * 64;
        #pragma unroll
        for (int j = 0; j < 4; ++j)
            slab64(WT, n0 + j * 64, k0, l + j * 64 * 64, wave, lane);
    };
    auto ldB = [&](int tb_) {
        const unsigned short* base = sB + tb_ * LB;
        #pragma unroll
        for (int nt = 0; nt < 4; ++nt)
            #pragma unroll
            for (int ks = 0; ks < 2; ++ks)
                bfr[nt][ks] = *(const bf16x8*)
                    &base[(wn * 64 + nt * 16 + li) * 64 + ((ks * 4 + lj) ^ swz) * 8];
    };
    auto ldA = [&](int tb_, int h, bf16x8 (*af)[2]) {
        const unsigned short* base = sA + tb_ * LA;
        #pragma unroll
        for (int m = 0; m < PM; ++m)
            #pragma unroll
            for (int ks = 0; ks < 2; ++ks)
                af[m][ks] = *(const bf16x8*)
                    &base[(wm * (BM / 2) + (h * PM + m) * 16 + li) * 64
                          + ((ks * 4 + lj) ^ swz) * 8];
    };
    auto mfma_h = [&](int h, bf16x8 (*af)[2]) {
        __builtin_amdgcn_s_setprio(1);
        #pragma unroll
        for (int ks = 0; ks < 2; ++ks)
            #pragma unroll
            for (int m = 0; m < PM; ++m)
                #pragma unroll
                for (int nt = 0; nt < 4; ++nt)
                    acc[h * PM + m][nt] = __builtin_amdgcn_mfma_f32_16x16x32_bf16(
                        af[m][ks], bfr[nt][ks], acc[h * PM + m][nt], 0, 0, 0);
        __builtin_amdgcn_s_setprio(0);
    };

    // prologue: tile 0 (A+B) + B(1); vmcnt(4) leaves B(1) in flight.
    stageAf(0); stageBf(0); stageBf(1);
    vmwait4();
    S_BARRIER();

    for (int i = 0; i < NT / 2; ++i) {
        const int ta = 2 * i, tb = 2 * i + 1;
        bf16x8 afh[PM][2];
        // ---- tile ta (buf0), phases 0-1 ----
        ldB(0); ldA(0, 0, afh);
        stageAf(tb);
        S_BARRIER(); mfma_h(0, afh); S_BARRIER();
        ldA(0, 1, afh);
        stageBf(ta + 2);
        S_BARRIER(); mfma_h(1, afh);
        vmwait4();                      // B(1)+A(tb) landed -> buf1 ready
        S_BARRIER();
        // ---- tile tb (buf1), phases 2-3 ----
        ldB(1); ldA(1, 0, afh);
        stageAf(ta + 2);
        S_BARRIER(); mfma_h(0, afh); S_BARRIER();
        ldA(1, 1, afh);
        stageBf(tb + 2);
        S_BARRIER(); mfma_h(1, afh);
        vmwait4();                      // B(ta+2)+A(ta+2) landed -> buf0 ready
        S_BARRIER();
    }
    vmwait0();
    S_BARRIER();

    // ------------------------------ epilogue ------------------------------
    if (MODE == 1) {
        #pragma unroll
        for (int mt = 0; mt < MT; ++mt)
            #pragma unroll
            for (int nt = 0; nt < 4; ++nt) {
                const int col = n0 + wn * 64 + nt * 16 + li;
                const float bb = b0[col];
                #pragma unroll
                for (int r = 0; r < 4; ++r) {
                    const int row = m0 + wm * (BM / 2) + mt * 16 + lj * 4 + r;
                    Cout[(size_t)row * HID_ + col] = acc[mt][nt][r] + bb;
                }
            }
        return;
    }

    int seg, cb; const float* bias;
    if (n0 < 2048)      { seg = 0; cb = n0;        bias = b0; }
    else if (n0 < 2560) { seg = 1; cb = n0 - 2048; bias = b1; }
    else                { seg = 2; cb = n0 - 2560; bias = b2; }

    float bl[4];
    #pragma unroll
    for (int nt = 0; nt < 4; ++nt) bl[nt] = bias[cb + wn * 64 + nt * 16 + li];

    if (seg == 2) {
        const int b = m0 >> 11;
        #pragma unroll
        for (int nt = 0; nt < 4; ++nt) {
            const int cseg = cb + wn * 64 + nt * 16 + li;
            const int hv = cseg >> 6, d = cseg & 63;
            #pragma unroll
            for (int mt = 0; mt < MT; ++mt) {
                const int sb = (m0 & (S_ - 1)) + wm * (BM / 2) + mt * 16 + lj * 4;
                u16x4 u = { f2bfu(acc[mt][nt][0] + bl[nt]),
                            f2bfu(acc[mt][nt][1] + bl[nt]),
                            f2bfu(acc[mt][nt][2] + bl[nt]),
                            f2bfu(acc[mt][nt][3] + bl[nt]) };
                *(u16x4*)((unsigned short*)Cv +
                    ((size_t)((b * NKV_ + hv) * 64 + d)) * S_ + sb) = u;
            }
        }
        return;
    }

    const float qs = (seg == 0) ? 0.18033688011112042f : 1.0f;
    #pragma unroll
    for (int mt = 0; mt < MT; ++mt) {
        #pragma unroll
        for (int r = 0; r < 4; ++r) {
            const int row = m0 + wm * (BM / 2) + mt * 16 + lj * 4 + r;
            const int s = row & (S_ - 1);
            const float c0  = ctab[s * 32 + li],      sn0 = stab[s * 32 + li];
            const float c1  = ctab[s * 32 + 16 + li], sn1 = stab[s * 32 + 16 + li];
            const float x0 = acc[mt][0][r] + bl[0];
            const float x1 = acc[mt][1][r] + bl[1];
            const float x2 = acc[mt][2][r] + bl[2];
            const float x3 = acc[mt][3][r] + bl[3];
            const float y0 = (x0 * c0 - x2 * sn0) * qs;
            const float y2 = (x2 * c0 + x0 * sn0) * qs;
            const float y1 = (x1 * c1 - x3 * sn1) * qs;
            const float y3 = (x3 * c1 + x1 * sn1) * qs;
            if (seg == 0) {
                bf16* cp = Cq + (size_t)row * HID_ + n0 + wn * 64 + li;
                cp[0]  = __float2bfloat16(y0);
                cp[16] = __float2bfloat16(y1);
                cp[32] = __float2bfloat16(y2);
                cp[48] = __float2bfloat16(y3);
            } else {
                bf16* cp = Ck + (size_t)row * 512 + cb + wn * 64 + li;
                cp[0]  = __float2bfloat16(y0);
                cp[16] = __float2bfloat16(y1);
                cp[32] = __float2bfloat16(y2);
                cp[48] = __float2bfloat16(y3);
            }
        }
    }
}

// ---------------------------------------------------------------------------
// MFMA flash attention v4: QBLK=256, 64 q-rows/wave, ILP-restructured.
// Round-5 counters: no pipe saturated (VALU 45%, LDS ~28%, MFMA 26%) ->
// dependency-serialized within each wave. Fix: issue ALL 32 QK MFMAs as one
// cluster (4 groups), then load V frags, then run the 4 softmaxes (VALU
// overlaps the in-flight MFMA + vf ds_read latency), then the PV cluster.
// Tree max-reduce (v_max3-fusable). blockIdx.y >= 64 -> absorbed wtrans.
// ---------------------------------------------------------------------------
__global__ __launch_bounds__(256, 2) void attn_k(
    const bf16* __restrict__ qws, const bf16* __restrict__ kws,
    const bf16* __restrict__ vtw, bf16* __restrict__ ows,
    const float* __restrict__ wo, bf16* __restrict__ woT)
{
    __shared__ unsigned short sMem[24576];   // 48 KB: sK(8K) | sVt(8K) | sP(32K)

    if (blockIdx.y >= 64) {
        const int t = (blockIdx.y - 64) * 8 + blockIdx.x;   // 0..1023 (32 x 32)
        wtrans_body(wo, 2048, wo, 0, wo, 0, woT, HID_, t & 31, t >> 5, sMem);
        return;
    }

    unsigned short* sK  = sMem;             // [key][dim], swizzled
    unsigned short* sVt = sMem + 4096;      // [dim][key], swizzled
    unsigned short* sP  = sMem + 8192;      // per-wave [4*16 q][key], swizzled

    const int tid  = threadIdx.x;
    const int wave = tid >> 6, lane = tid & 63;
    const int li   = lane & 15, lj = lane >> 4;
    const int bh   = blockIdx.y;
    const int q0   = blockIdx.x * 256;
    const int b    = bh / NH_, h = bh % NH_;
    const int hk   = h / G_;

    bf16x8 qf[4][2];
    #pragma unroll
    for (int g = 0; g < 4; g++) {
        const bf16* qp = qws + (size_t)(b * S_ + q0 + wave * 64 + g * 16 + li) * HID_
                         + h * D_ + lj * 8;
        qf[g][0] = *(const bf16x8*)(qp);
        qf[g][1] = *(const bf16x8*)(qp + 32);
    }

    f32x4 o[4][4];
    #pragma unroll
    for (int g = 0; g < 4; g++)
        #pragma unroll
        for (int mt = 0; mt < 4; mt++) o[g][mt] = (f32x4){0.f, 0.f, 0.f, 0.f};
    float mr[4] = {-1e30f, -1e30f, -1e30f, -1e30f};
    float ll[4] = {0.f, 0.f, 0.f, 0.f};

    const int srow = tid >> 2, scol = (tid & 3) * 16;
    const bf16* kb = kws + (size_t)b * S_ * 512 + hk * 64;
    const bf16* vb = vtw + (size_t)((b * NKV_ + hk) * 64) * S_;
    unsigned short* sp = sP + wave * (64 * 64);

    uint4 pk0, pk1, pv0, pv1;
    {
        const uint4* kp = (const uint4*)(kb + (size_t)srow * 512 + scol);
        const uint4* vp = (const uint4*)(vb + (size_t)srow * S_ + scol);
        pk0 = kp[0]; pk1 = kp[1]; pv0 = vp[0]; pv1 = vp[1];
    }

    for (int kt = 0; kt < S_; kt += 64) {
        __syncthreads();
        *(uint4*)&sK [srow * 64 + SWZ(srow, scol)]     = pk0;
        *(uint4*)&sK [srow * 64 + SWZ(srow, scol + 8)] = pk1;
        *(uint4*)&sVt[srow * 64 + SWZ(srow, scol)]     = pv0;
        *(uint4*)&sVt[srow * 64 + SWZ(srow, scol + 8)] = pv1;
        __syncthreads();

        if (kt + 64 < S_) {
            const uint4* kp = (const uint4*)(kb + (size_t)(kt + 64 + srow) * 512 + scol);
            const uint4* vp = (const uint4*)(vb + (size_t)srow * S_ + kt + 64 + scol);
            pk0 = kp[0]; pk1 = kp[1]; pv0 = vp[0]; pv1 = vp[1];
        }

        // K frags into registers
        bf16x8 kf[4][2];
        #pragma unroll
        for (int nt = 0; nt < 4; nt++)
            #pragma unroll
            for (int ks = 0; ks < 2; ks++)
                kf[nt][ks] = *(const bf16x8*)&sK[(nt * 16 + li) * 64
                                                 + SWZ(li, ks * 32 + lj * 8)];

        // ---- QK^T: all 4 q-groups as one 32-MFMA cluster ----
        f32x4 c[4][4];
        __builtin_amdgcn_s_setprio(1);
        #pragma unroll
        for (int g = 0; g < 4; g++)
            #pragma unroll
            for (int nt = 0; nt < 4; nt++) {
                f32x4 t = (f32x4){0.f, 0.f, 0.f, 0.f};
                t = __builtin_amdgcn_mfma_f32_16x16x32_bf16(kf[nt][0], qf[g][0], t, 0, 0, 0);
                t = __builtin_amdgcn_mfma_f32_16x16x32_bf16(kf[nt][1], qf[g][1], t, 0, 0, 0);
                c[g][nt] = t;
            }
        __builtin_amdgcn_s_setprio(0);

        // V frags now: ds_read latency hides under the softmax VALU below
        bf16x8 vf[4][2];
        #pragma unroll
        for (int mt = 0; mt < 4; mt++)
            #pragma unroll
            for (int ks = 0; ks < 2; ks++)
                vf[mt][ks] = *(const bf16x8*)&sVt[(mt * 16 + li) * 64
                                                  + SWZ(li, ks * 32 + lj * 8)];

        // ---- softmax per q-group (runs while QK MFMAs/vf reads retire) ----
        #pragma unroll
        for (int g = 0; g < 4; g++) {
            float m0a = fmaxf(fmaxf(c[g][0][0], c[g][0][1]),
                              fmaxf(c[g][0][2], c[g][0][3]));
            float m1a = fmaxf(fmaxf(c[g][1][0], c[g][1][1]),
                              fmaxf(c[g][1][2], c[g][1][3]));
            float m2a = fmaxf(fmaxf(c[g][2][0], c[g][2][1]),
                              fmaxf(c[g][2][2], c[g][2][3]));
            float m3a = fmaxf(fmaxf(c[g][3][0], c[g][3][1]),
                              fmaxf(c[g][3][2], c[g][3][3]));
            float cm = fmaxf(fmaxf(m0a, m1a), fmaxf(m2a, m3a));
            cm = fmaxf(cm, __shfl_xor(cm, 16));
            cm = fmaxf(cm, __shfl_xor(cm, 32));
            if (!__all(cm - mr[g] <= 8.0f)) {
                const float mnew = fmaxf(mr[g], cm);
                const float al   = fexp2(mr[g] - mnew);
                mr[g] = mnew;
                ll[g] *= al;
                #pragma unroll
                for (int mt = 0; mt < 4; mt++) o[g][mt] *= al;
            }
            float rs = 0.f;
            #pragma unroll
            for (int nt = 0; nt < 4; nt++) {
                const float e0 = fexp2(c[g][nt][0] - mr[g]);
                const float e1 = fexp2(c[g][nt][1] - mr[g]);
                const float e2 = fexp2(c[g][nt][2] - mr[g]);
                const float e3 = fexp2(c[g][nt][3] - mr[g]);
                rs += (e0 + e1) + (e2 + e3);
                u16x4 u = { f2bfu(e0), f2bfu(e1), f2bfu(e2), f2bfu(e3) };
                *(u16x4*)&sp[(g * 16 + li) * 64 + SWZ(li, nt * 16 + lj * 4)] = u;
            }
            ll[g] += rs;   // lane-local partial; reduced once in epilogue
        }

        // ---- PV: one 32-MFMA cluster ----
        __builtin_amdgcn_s_setprio(1);
        #pragma unroll
        for (int g = 0; g < 4; g++) {
            #pragma unroll
            for (int ks = 0; ks < 2; ks++) {
                const bf16x8 pf = *(const bf16x8*)&sp[(g * 16 + li) * 64
                                                      + SWZ(li, ks * 32 + lj * 8)];
                #pragma unroll
                for (int mt = 0; mt < 4; mt++)
                    o[g][mt] = __builtin_amdgcn_mfma_f32_16x16x32_bf16(
                        vf[mt][ks], pf, o[g][mt], 0, 0, 0);
            }
        }
        __builtin_amdgcn_s_setprio(0);
    }

    #pragma unroll
    for (int g = 0; g < 4; g++) {
        float l = ll[g];
        l += __shfl_xor(l, 16);
        l += __shfl_xor(l, 32);
        const float inv = 1.0f / l;
        bf16* op = ows + (size_t)(b * S_ + q0 + wave * 64 + g * 16 + li) * HID_ + h * D_;
        #pragma unroll
        for (int mt = 0; mt < 4; mt++) {
            u16x4 u = { f2bfu(o[g][mt][0] * inv), f2bfu(o[g][mt][1] * inv),
                        f2bfu(o[g][mt][2] * inv), f2bfu(o[g][mt][3] * inv) };
            *(u16x4*)((unsigned short*)op + mt * 16 + lj * 4) = u;
        }
    }
}

// ---------------------------------------------------------------------------
extern "C" void kernel_launch(void* const* d_in, const int* in_sizes, int n_in,
                              void* d_out, int out_size, void* d_ws, size_t ws_size,
                              hipStream_t stream)
{
    const float* hs  = (const float*)d_in[0];
    const int*   pos = (const int*)d_in[1];
    const float* wq = (const float*)d_in[2];
    const float* bq = (const float*)d_in[3];
    const float* wk = (const float*)d_in[4];
    const float* bk = (const float*)d_in[5];
    const float* wv = (const float*)d_in[6];
    const float* bv = (const float*)d_in[7];
    const float* wo = (const float*)d_in[8];
    const float* bo = (const float*)d_in[9];

    // workspace (52.5 MB peak)
    char* ws = (char*)d_ws;
    float* ctab  = (float*)(ws);
    float* stab  = (float*)(ws + (256u << 10));
    bf16*  k_ws  = (bf16*)(ws + (512u << 10));
    bf16*  v_t   = (bf16*)(ws + (512u << 10) + (4u  << 20));
    bf16*  q_ws  = (bf16*)(ws + (512u << 10) + (8u  << 20));
    bf16*  hs_b  = (bf16*)(ws + (512u << 10) + (24u << 20));
    bf16*  o_ws  = hs_b;                                   // overlay
    bf16*  wqkvT = (bf16*)(ws + (512u << 10) + (40u << 20));
    bf16*  woT   = wqkvT;                                  // overlay (dead after gemm<0>)

    // prep: cvt (4096) + wtrans qkv (1536) + rope (256)
    prep_k<<<dim3(5888), dim3(256), 0, stream>>>(
        hs, hs_b, wq, wk, wv, wqkvT, pos, ctab, stab);

    // QKV: BM=256, BN=256 -> grid 12 x 16 = 192 blocks
    gemm4p_k<0, 256><<<dim3(12, 16), dim3(512), 0, stream>>>(
        hs_b, wqkvT, bq, bk, bv, q_ws, k_ws, v_t, nullptr, ctab, stab);

    // attn (y<64, QBLK=256) + absorbed wtrans wo -> woT (y in [64,192))
    attn_k<<<dim3(8, 192), dim3(256), 0, stream>>>(
        q_ws, k_ws, v_t, o_ws, wo, woT);

    // OUT: BM=128, BN=256 -> grid 8 x 32 = 256 blocks (exactly 1/CU)
    gemm4p_k<1, 128><<<dim3(8, 32), dim3(512), 0, stream>>>(
        o_ws, woT, bo, nullptr, nullptr, nullptr, nullptr, nullptr,
        (float*)d_out, nullptr, nullptr);
}